// Round 5
// baseline (991.880 us; speedup 1.0000x reference)
//
#include <hip/hip_runtime.h>
#include <hip/hip_bf16.h>

#define N_ROWS 4096
#define H_DIM  512
#define V_DIM  50257
#define BM 128
#define BN 128
#define BK 64
#define NSTEP (H_DIM / BK)      // 8
#define VT_TOTAL 393            // ceil(V/BN)
#define V_PAD (VT_TOTAL * BN)   // 50304
#define NCHUNK 131              // 393 = 3*131 -> every block exactly 3 tiles
#define LOG2E 1.4426950408889634f
#define BUF0 0
#define BUF1 32768

typedef __attribute__((ext_vector_type(8))) short short8;
typedef __attribute__((ext_vector_type(4))) float f32x4;

static __device__ __forceinline__ unsigned short f2bf(float f) {
  unsigned u = __float_as_uint(f);
  u = (u + 0x7fffu + ((u >> 16) & 1u)) >> 16;   // RNE
  return (unsigned short)u;
}

static __device__ __forceinline__ void gload_lds16(const void* g, void* l) {
  __builtin_amdgcn_global_load_lds(
      (const __attribute__((address_space(1))) void*)g,
      (__attribute__((address_space(3))) void*)l, 16, 0, 0);
}

// ---------------- kernel A: fp32 -> bf16 conversion (W padded to V_PAD) ----
__global__ void convert_kernel(const float* __restrict__ X,
                               const float* __restrict__ W,
                               __hip_bfloat16* __restrict__ Xb,
                               __hip_bfloat16* __restrict__ Wb) {
  const long wtot8 = (long)V_PAD * H_DIM / 8;   // 3,219,456
  const long xtot8 = (long)N_ROWS * H_DIM / 8;  //   262,144
  long i = (long)blockIdx.x * blockDim.x + threadIdx.x;
  unsigned short o[8];
  if (i < wtot8) {
    long base = i * 8;
    long row = base >> 9;   // /512
    if (row < V_DIM) {
      const float4* s = (const float4*)(W + base);
      float4 a = s[0], b = s[1];
      o[0]=f2bf(a.x); o[1]=f2bf(a.y); o[2]=f2bf(a.z); o[3]=f2bf(a.w);
      o[4]=f2bf(b.x); o[5]=f2bf(b.y); o[6]=f2bf(b.z); o[7]=f2bf(b.w);
    } else {
      #pragma unroll
      for (int k = 0; k < 8; ++k) o[k] = 0;
    }
    *(short8*)(Wb + base) = *(const short8*)o;
  } else if (i < wtot8 + xtot8) {
    long base = (i - wtot8) * 8;
    const float4* s = (const float4*)(X + base);
    float4 a = s[0], b = s[1];
    o[0]=f2bf(a.x); o[1]=f2bf(a.y); o[2]=f2bf(a.z); o[3]=f2bf(a.w);
    o[4]=f2bf(b.x); o[5]=f2bf(b.y); o[6]=f2bf(b.z); o[7]=f2bf(b.w);
    *(short8*)(Xb + base) = *(const short8*)o;
  }
}

// epilogue: stats update from register-prefetched targets/bias.
// Thread owns 4 x-rows (a, c15) x 16 vocab cols (v0 + b*16 + j).
template <bool GUARD>
static __device__ __forceinline__ void epilogue(
    const f32x4 (&tp)[4][4], const f32x4 (&bp)[4], int v0,
    const f32x4 (&acc)[4][4],
    float ml[4], float sl[4], float mt[4], float st[4], float dd[4]) {
  #pragma unroll
  for (int a = 0; a < 4; ++a) {
    #pragma unroll
    for (int h = 0; h < 2; ++h) {          // halves: b = {2h, 2h+1}
      float T[8], L[8];
      #pragma unroll
      for (int bb = 0; bb < 2; ++bb) {
        const int b = 2 * h + bb;
        #pragma unroll
        for (int j = 0; j < 4; ++j) {
          const int k = bb * 4 + j;
          const bool ok = !GUARD || (v0 + b * 16 + j < V_DIM);
          L[k] = ok ? (acc[a][b][j] + bp[b][j]) : -1e30f;
          T[k] = ok ? tp[a][b][j] : -1e30f;
        }
      }
      // logits lse (online, defer-max thr=12)
      float g = fmaxf(fmaxf(fmaxf(L[0], L[1]), fmaxf(L[2], L[3])),
                      fmaxf(fmaxf(L[4], L[5]), fmaxf(L[6], L[7])));
      if (g > ml[a] + 12.f) {
        sl[a] *= exp2f((ml[a] - g) * LOG2E);
        ml[a] = g;
      }
      float bl = ml[a] * LOG2E;
      float ss = 0.f;
      #pragma unroll
      for (int k = 0; k < 8; ++k)
        ss += exp2f(__builtin_fmaf(L[k], LOG2E, -bl));
      sl[a] += ss;
      // targets softmax num/denom (online, defer-max thr=12)
      float gt = fmaxf(fmaxf(fmaxf(T[0], T[1]), fmaxf(T[2], T[3])),
                       fmaxf(fmaxf(T[4], T[5]), fmaxf(T[6], T[7])));
      if (gt > mt[a] + 12.f) {
        float sc = exp2f((mt[a] - gt) * LOG2E);
        st[a] *= sc; dd[a] *= sc; mt[a] = gt;
      }
      float bt = mt[a] * LOG2E;
      float s2 = 0.f, d2 = 0.f;
      #pragma unroll
      for (int k = 0; k < 8; ++k) {
        float e = exp2f(__builtin_fmaf(T[k], LOG2E, -bt));
        s2 += e;
        d2 = __builtin_fmaf(e, L[k], d2);
      }
      st[a] += s2; dd[a] += d2;
    }
  }
}

// ---------------- kernel B: fused GEMM + online softmax stats -------------
// Grid (32, NCHUNK). Block 256 = 4 waves (2x2 over the 128x128 tile).
// BK=64, double-buffered 2-phase pipeline: stage(next) -> compute(cur) ->
// barrier. LDS XOR-swizzle: linear writes via pre-swizzled global source,
// swizzled ds_read (^((c15&7)<<4)) -> 2-way bank access (free).
__global__ __launch_bounds__(256, 2)
void fused_kernel(const __hip_bfloat16* __restrict__ Xb,
                  const __hip_bfloat16* __restrict__ Wb,
                  const float* __restrict__ bias,
                  const float* __restrict__ targets,
                  float* __restrict__ partials) {
  __shared__ __align__(16) char smem[65536];   // 2 x {A 16K, B 16K}

  const int tid  = threadIdx.x;
  const int lane = tid & 63;
  const int wid  = tid >> 6;
  const int wm   = wid >> 1;
  const int wn   = wid & 1;
  const int q    = lane >> 4;
  const int c15  = lane & 15;
  const int brow = blockIdx.x;
  const int chunk = blockIdx.y;

  float ml[4], sl[4], mt[4], st[4], dd[4];
  #pragma unroll
  for (int a = 0; a < 4; ++a) {
    ml[a] = -1e30f; sl[a] = 0.f; mt[a] = -1e30f; st[a] = 0.f; dd[a] = 0.f;
  }

  // staging precompute: thread t writes LDS bytes [i*4096 + t*16) linearly;
  // source element offset pre-swizzled so a swizzled ds_read reads it back.
  const int srow8 = tid >> 3;                               // 0..31
  const int soff  = ((tid & 7) * 8) ^ ((srow8 & 7) * 8);    // elems in [0,64)
  const __hip_bfloat16* asrc = Xb + (long)(brow * BM + srow8) * H_DIM + soff;

  // read precompute
  const int rm      = (c15 & 7) << 4;          // byte XOR mask
  const int arow_b  = (wm * 64 + c15) * 128;   // + a*2048
  const int brow_b  = (wn * 64 + c15) * 128;   // + b*2048 (+16384 A-region)

  auto stage = [&](int bufb, const __hip_bfloat16* a_s,
                   const __hip_bfloat16* b_s, int kk) {
    #pragma unroll
    for (int i = 0; i < 4; ++i)
      gload_lds16(a_s + (long)i * 32 * H_DIM + kk,
                  smem + bufb + i * 4096 + tid * 16);
    #pragma unroll
    for (int i = 0; i < 4; ++i)
      gload_lds16(b_s + (long)i * 32 * H_DIM + kk,
                  smem + bufb + 16384 + i * 4096 + tid * 16);
  };

  // per-thread target row base
  const long trow0 = (long)(brow * BM + wm * 64 + c15) * V_DIM;
  const long tlim  = (long)N_ROWS * V_DIM - 4;

  // prologue: stage first tile's k=0 into buf0
  const __hip_bfloat16* bsrc = Wb + (long)(chunk * BN + srow8) * H_DIM + soff;
  stage(BUF0, asrc, bsrc, 0);
  __syncthreads();

  #pragma unroll 1
  for (int vt = chunk; vt < VT_TOTAL; vt += NCHUNK) {
    const int vbase = vt * BN;
    const int v0 = vbase + wn * 64 + q * 4;
    const bool last = (vt + NCHUNK >= VT_TOTAL);
    const __hip_bfloat16* bsrc_next =
        Wb + (long)((vt + NCHUNK) * BN + srow8) * H_DIM + soff;

    // ---- register prefetch: 16x targets float4 + 4x bias float4 ----
    f32x4 tp[4][4];
    f32x4 bp[4];
    #pragma unroll
    for (int b = 0; b < 4; ++b) {
      int bo = v0 + b * 16;
      bo = bo > (V_DIM - 4) ? (V_DIM - 4) : bo;
      bp[b] = *(const f32x4*)(bias + bo);
    }
    #pragma unroll
    for (int a = 0; a < 4; ++a) {
      const long rb = trow0 + (long)a * 16 * V_DIM + v0;
      #pragma unroll
      for (int b = 0; b < 4; ++b) {
        long off = rb + b * 16;
        off = off > tlim ? tlim : off;
        tp[a][b] = *(const f32x4*)(targets + off);
      }
    }

    f32x4 acc[4][4];
    #pragma unroll
    for (int a = 0; a < 4; ++a)
      #pragma unroll
      for (int b = 0; b < 4; ++b)
        acc[a][b] = (f32x4){0.f, 0.f, 0.f, 0.f};

    // ---- 2-phase pipelined K-loop: stage(next) -> compute(cur) -> bar ----
    #pragma unroll
    for (int ks = 0; ks < NSTEP; ++ks) {
      const int cb = (ks & 1) ? BUF1 : BUF0;
      const int nb = (ks & 1) ? BUF0 : BUF1;
      if (ks < NSTEP - 1)
        stage(nb, asrc, bsrc, (ks + 1) * BK);
      else if (!last)
        stage(nb, asrc, bsrc_next, 0);   // cross-tile prefetch of next k=0

      #pragma unroll
      for (int s = 0; s < 2; ++s) {
        short8 xf[4], wf[4];
        #pragma unroll
        for (int a = 0; a < 4; ++a)
          xf[a] = *(const short8*)(smem + cb + arow_b + a * 2048 +
                                   ((s * 64 + q * 16) ^ rm));
        #pragma unroll
        for (int b = 0; b < 4; ++b)
          wf[b] = *(const short8*)(smem + cb + 16384 + brow_b + b * 2048 +
                                   ((s * 64 + q * 16) ^ rm));
        #pragma unroll
        for (int a = 0; a < 4; ++a)
          #pragma unroll
          for (int b = 0; b < 4; ++b)
            acc[a][b] = __builtin_amdgcn_mfma_f32_16x16x32_bf16(
                wf[b], xf[a], acc[a][b], 0, 0, 0);
      }
      __syncthreads();
    }
    bsrc = bsrc_next;

    if (vt == VT_TOTAL - 1)
      epilogue<true>(tp, bp, v0, acc, ml, sl, mt, st, dd);
    else
      epilogue<false>(tp, bp, v0, acc, ml, sl, mt, st, dd);
  }

  // merge the 4 q-lanes (lane bits 4,5) holding disjoint vocab slices
  #pragma unroll
  for (int off = 16; off <= 32; off <<= 1) {
    #pragma unroll
    for (int a = 0; a < 4; ++a) {
      float ml2 = __shfl_xor(ml[a], off);
      float sl2 = __shfl_xor(sl[a], off);
      float mt2 = __shfl_xor(mt[a], off);
      float st2 = __shfl_xor(st[a], off);
      float dd2 = __shfl_xor(dd[a], off);
      float nm = fmaxf(ml[a], ml2);
      sl[a] = sl[a] * exp2f((ml[a] - nm) * LOG2E) + sl2 * exp2f((ml2 - nm) * LOG2E);
      ml[a] = nm;
      float nmt = fmaxf(mt[a], mt2);
      float e1 = exp2f((mt[a] - nmt) * LOG2E);
      float e2 = exp2f((mt2 - nmt) * LOG2E);
      st[a] = st[a] * e1 + st2 * e2;
      dd[a] = dd[a] * e1 + dd2 * e2;
      mt[a] = nmt;
    }
  }

  // cross-wn merge via LDS, one partial per (row, chunk)
  __syncthreads();
  float* M = (float*)smem;   // 128 rows x 5 floats = 2560 B
  if (wn == 1 && q == 0) {
    #pragma unroll
    for (int a = 0; a < 4; ++a) {
      int r = wm * 64 + a * 16 + c15;
      float* p = M + r * 5;
      p[0] = ml[a]; p[1] = sl[a]; p[2] = mt[a]; p[3] = st[a]; p[4] = dd[a];
    }
  }
  __syncthreads();
  if (wn == 0 && q == 0) {
    #pragma unroll
    for (int a = 0; a < 4; ++a) {
      int r = wm * 64 + a * 16 + c15;
      const float* p = M + r * 5;
      float ml2 = p[0], sl2 = p[1], mt2 = p[2], st2 = p[3], dd2 = p[4];
      float nm = fmaxf(ml[a], ml2);
      float slo = sl[a] * exp2f((ml[a] - nm) * LOG2E) + sl2 * exp2f((ml2 - nm) * LOG2E);
      float nmt = fmaxf(mt[a], mt2);
      float e1 = exp2f((mt[a] - nmt) * LOG2E);
      float e2 = exp2f((mt2 - nmt) * LOG2E);
      float sto = st[a] * e1 + st2 * e2;
      float ddo = dd[a] * e1 + dd2 * e2;
      long rg = (long)(brow * BM + r);
      float* o = partials + (rg * NCHUNK + chunk) * 5;
      o[0] = nm; o[1] = slo; o[2] = nmt; o[3] = sto; o[4] = ddo;
    }
  }
}

// ---------------- kernel C: merge partials -> per-row loss ----------------
__global__ void rowloss_kernel(const float* __restrict__ partials,
                               float* __restrict__ rowloss) {
  int r = blockIdx.x * blockDim.x + threadIdx.x;
  if (r >= N_ROWS) return;
  const float* p = partials + (long)r * NCHUNK * 5;
  float ml = -1e30f, sl = 0.f, mt = -1e30f, st = 0.f, dd = 0.f;
  for (int c = 0; c < NCHUNK; ++c) {
    float ml2 = p[0], sl2 = p[1], mt2 = p[2], st2 = p[3], dd2 = p[4];
    p += 5;
    float nm = fmaxf(ml, ml2);
    sl = sl * exp2f((ml - nm) * LOG2E) + sl2 * exp2f((ml2 - nm) * LOG2E);
    ml = nm;
    float nmt = fmaxf(mt, mt2);
    float e1 = exp2f((mt - nmt) * LOG2E);
    float e2 = exp2f((mt2 - nmt) * LOG2E);
    st = st * e1 + st2 * e2;
    dd = dd * e1 + dd2 * e2;
    mt = nmt;
  }
  float lse = ml + logf(sl);
  rowloss[r] = lse - dd / st;
}

// ---------------- kernel D: final scalar reduce ---------------------------
__global__ void final_kernel(const float* __restrict__ rowloss,
                             float* __restrict__ out) {
  __shared__ float sm[4];
  float s = 0.f;
  for (int i = threadIdx.x; i < N_ROWS; i += 256) s += rowloss[i];
  #pragma unroll
  for (int off = 32; off > 0; off >>= 1) s += __shfl_down(s, off);
  if ((threadIdx.x & 63) == 0) sm[threadIdx.x >> 6] = s;
  __syncthreads();
  if (threadIdx.x == 0) out[0] = (sm[0] + sm[1] + sm[2] + sm[3]) * (1.0f / (float)N_ROWS);
}

extern "C" void kernel_launch(void* const* d_in, const int* in_sizes, int n_in,
                              void* d_out, int out_size, void* d_ws, size_t ws_size,
                              hipStream_t stream) {
  const float* x       = (const float*)d_in[0];   // [4096, 512]
  const float* targets = (const float*)d_in[1];   // [4096, 50257]
  const float* weight  = (const float*)d_in[2];   // [50257, 512]
  const float* bias    = (const float*)d_in[3];   // [50257]
  float* out = (float*)d_out;

  char* ws = (char*)d_ws;
  __hip_bfloat16* Wb = (__hip_bfloat16*)ws;                     // 51,511,296 B
  size_t off = (size_t)V_PAD * H_DIM * 2;
  __hip_bfloat16* Xb = (__hip_bfloat16*)(ws + off);             //  4,194,304 B
  off += (size_t)N_ROWS * H_DIM * 2;
  float* partials = (float*)(ws + off);                         // 10,731,520 B
  off += (size_t)N_ROWS * NCHUNK * 5 * sizeof(float);
  float* rowloss = (float*)(ws + off);                          //     16,384 B

  convert_kernel<<<13600, 256, 0, stream>>>(x, weight, Xb, Wb);
  dim3 grid(N_ROWS / BM, NCHUNK);
  fused_kernel<<<grid, 256, 0, stream>>>(Xb, Wb, bias, targets, partials);
  rowloss_kernel<<<N_ROWS / 256, 256, 0, stream>>>(partials, rowloss);
  final_kernel<<<1, 256, 0, stream>>>(rowloss, out);
}

// Round 6
// 979.962 us; speedup vs baseline: 1.0122x; 1.0122x over previous
//
#include <hip/hip_runtime.h>
#include <hip/hip_bf16.h>

#define N_ROWS 4096
#define H_DIM  512
#define V_DIM  50257
#define BM 128
#define BN 128
#define BK 64
#define NSTEP (H_DIM / BK)      // 8
#define VT_TOTAL 393            // ceil(V/BN)
#define V_PAD (VT_TOTAL * BN)   // 50304
#define NCHUNK 131              // 393 = 3*131 -> every block exactly 3 tiles
#define LOG2E 1.4426950408889634f
#define BUF0 0
#define BUF1 32768

typedef __attribute__((ext_vector_type(8))) short short8;
typedef __attribute__((ext_vector_type(4))) float f32x4;

static __device__ __forceinline__ unsigned short f2bf(float f) {
  unsigned u = __float_as_uint(f);
  u = (u + 0x7fffu + ((u >> 16) & 1u)) >> 16;   // RNE
  return (unsigned short)u;
}

static __device__ __forceinline__ void gload_lds16(const void* g, void* l) {
  __builtin_amdgcn_global_load_lds(
      (const __attribute__((address_space(1))) void*)g,
      (__attribute__((address_space(3))) void*)l, 16, 0, 0);
}

// ---------------- kernel A: fp32 -> bf16 conversion (W padded to V_PAD) ----
__global__ void convert_kernel(const float* __restrict__ X,
                               const float* __restrict__ W,
                               __hip_bfloat16* __restrict__ Xb,
                               __hip_bfloat16* __restrict__ Wb) {
  const long wtot8 = (long)V_PAD * H_DIM / 8;   // 3,219,456
  const long xtot8 = (long)N_ROWS * H_DIM / 8;  //   262,144
  long i = (long)blockIdx.x * blockDim.x + threadIdx.x;
  unsigned short o[8];
  if (i < wtot8) {
    long base = i * 8;
    long row = base >> 9;   // /512
    if (row < V_DIM) {
      const float4* s = (const float4*)(W + base);
      float4 a = s[0], b = s[1];
      o[0]=f2bf(a.x); o[1]=f2bf(a.y); o[2]=f2bf(a.z); o[3]=f2bf(a.w);
      o[4]=f2bf(b.x); o[5]=f2bf(b.y); o[6]=f2bf(b.z); o[7]=f2bf(b.w);
    } else {
      #pragma unroll
      for (int k = 0; k < 8; ++k) o[k] = 0;
    }
    *(short8*)(Wb + base) = *(const short8*)o;
  } else if (i < wtot8 + xtot8) {
    long base = (i - wtot8) * 8;
    const float4* s = (const float4*)(X + base);
    float4 a = s[0], b = s[1];
    o[0]=f2bf(a.x); o[1]=f2bf(a.y); o[2]=f2bf(a.z); o[3]=f2bf(a.w);
    o[4]=f2bf(b.x); o[5]=f2bf(b.y); o[6]=f2bf(b.z); o[7]=f2bf(b.w);
    *(short8*)(Xb + base) = *(const short8*)o;
  }
}

// epilogue for TWO row-groups a = a0, a0+1 (halved register footprint)
template <bool GUARD>
static __device__ __forceinline__ void epi2(
    const f32x4 (&tp)[2][4], const f32x4 (&bp)[4], int v0, int a0,
    const f32x4 (&acc)[4][4],
    float ml[4], float sl[4], float mt[4], float st[4], float dd[4]) {
  #pragma unroll
  for (int r = 0; r < 2; ++r) {
    const int a = a0 + r;
    #pragma unroll
    for (int h = 0; h < 2; ++h) {          // halves: b = {2h, 2h+1}
      float T[8], L[8];
      #pragma unroll
      for (int bb = 0; bb < 2; ++bb) {
        const int b = 2 * h + bb;
        #pragma unroll
        for (int j = 0; j < 4; ++j) {
          const int k = bb * 4 + j;
          const bool ok = !GUARD || (v0 + b * 16 + j < V_DIM);
          L[k] = ok ? (acc[a][b][j] + bp[b][j]) : -1e30f;
          T[k] = ok ? tp[r][b][j] : -1e30f;
        }
      }
      // logits lse (online, defer-max thr=12)
      float g = fmaxf(fmaxf(fmaxf(L[0], L[1]), fmaxf(L[2], L[3])),
                      fmaxf(fmaxf(L[4], L[5]), fmaxf(L[6], L[7])));
      if (g > ml[a] + 12.f) {
        sl[a] *= exp2f((ml[a] - g) * LOG2E);
        ml[a] = g;
      }
      float bl = ml[a] * LOG2E;
      float ss = 0.f;
      #pragma unroll
      for (int k = 0; k < 8; ++k)
        ss += exp2f(__builtin_fmaf(L[k], LOG2E, -bl));
      sl[a] += ss;
      // targets softmax num/denom (online, defer-max thr=12)
      float gt = fmaxf(fmaxf(fmaxf(T[0], T[1]), fmaxf(T[2], T[3])),
                       fmaxf(fmaxf(T[4], T[5]), fmaxf(T[6], T[7])));
      if (gt > mt[a] + 12.f) {
        float sc = exp2f((mt[a] - gt) * LOG2E);
        st[a] *= sc; dd[a] *= sc; mt[a] = gt;
      }
      float bt = mt[a] * LOG2E;
      float s2 = 0.f, d2 = 0.f;
      #pragma unroll
      for (int k = 0; k < 8; ++k) {
        float e = exp2f(__builtin_fmaf(T[k], LOG2E, -bt));
        s2 += e;
        d2 = __builtin_fmaf(e, L[k], d2);
      }
      st[a] += s2; dd[a] += d2;
    }
  }
}

// ---------------- kernel B: fused GEMM + online softmax stats -------------
// Grid (32, NCHUNK). Block 256 = 4 waves (2x2 over the 128x128 tile).
// BK=64 double-buffered 2-phase K-loop; LDS XOR-swizzle (linear writes via
// pre-swizzled global source). Targets register-prefetch split in TWO halves
// (rows a={0,1} before K-loop, a={2,3} after) to avoid scratch spill.
__global__ __launch_bounds__(256, 2)
void fused_kernel(const __hip_bfloat16* __restrict__ Xb,
                  const __hip_bfloat16* __restrict__ Wb,
                  const float* __restrict__ bias,
                  const float* __restrict__ targets,
                  float* __restrict__ partials) {
  __shared__ __align__(16) char smem[65536];   // 2 x {A 16K, B 16K}

  const int tid  = threadIdx.x;
  const int lane = tid & 63;
  const int wid  = tid >> 6;
  const int wm   = wid >> 1;
  const int wn   = wid & 1;
  const int q    = lane >> 4;
  const int c15  = lane & 15;
  const int brow = blockIdx.x;
  const int chunk = blockIdx.y;

  float ml[4], sl[4], mt[4], st[4], dd[4];
  #pragma unroll
  for (int a = 0; a < 4; ++a) {
    ml[a] = -1e30f; sl[a] = 0.f; mt[a] = -1e30f; st[a] = 0.f; dd[a] = 0.f;
  }

  // staging precompute: thread t writes LDS bytes linearly; source element
  // offset pre-swizzled so a swizzled ds_read reads it back.
  const int srow8 = tid >> 3;                               // 0..31
  const int soff  = ((tid & 7) * 8) ^ ((srow8 & 7) * 8);    // elems in [0,64)
  const __hip_bfloat16* asrc = Xb + (long)(brow * BM + srow8) * H_DIM + soff;

  // read precompute
  const int rm      = (c15 & 7) << 4;          // byte XOR mask
  const int arow_b  = (wm * 64 + c15) * 128;   // + a*2048
  const int brow_b  = (wn * 64 + c15) * 128;   // + b*2048 (+16384 A-region)

  auto stage = [&](int bufb, const __hip_bfloat16* a_s,
                   const __hip_bfloat16* b_s, int kk) {
    #pragma unroll
    for (int i = 0; i < 4; ++i)
      gload_lds16(a_s + (long)i * 32 * H_DIM + kk,
                  smem + bufb + i * 4096 + tid * 16);
    #pragma unroll
    for (int i = 0; i < 4; ++i)
      gload_lds16(b_s + (long)i * 32 * H_DIM + kk,
                  smem + bufb + 16384 + i * 4096 + tid * 16);
  };

  // per-thread target row base
  const long trow0 = (long)(brow * BM + wm * 64 + c15) * V_DIM;
  const long tlim  = (long)N_ROWS * V_DIM - 4;

  // prologue: stage first tile's k=0 into buf0
  const __hip_bfloat16* bsrc = Wb + (long)(chunk * BN + srow8) * H_DIM + soff;
  stage(BUF0, asrc, bsrc, 0);
  __syncthreads();

  #pragma unroll 1
  for (int vt = chunk; vt < VT_TOTAL; vt += NCHUNK) {
    const int vbase = vt * BN;
    const int v0 = vbase + wn * 64 + q * 4;
    const bool last = (vt + NCHUNK >= VT_TOTAL);
    const __hip_bfloat16* bsrc_next =
        Wb + (long)((vt + NCHUNK) * BN + srow8) * H_DIM + soff;

    // ---- register prefetch, FIRST HALF: rows a={0,1} + bias ----
    f32x4 tpA[2][4], tpB[2][4];
    f32x4 bp[4];
    #pragma unroll
    for (int b = 0; b < 4; ++b) {
      int bo = v0 + b * 16;
      bo = bo > (V_DIM - 4) ? (V_DIM - 4) : bo;
      bp[b] = *(const f32x4*)(bias + bo);
    }
    #pragma unroll
    for (int r = 0; r < 2; ++r) {
      const long rb = trow0 + (long)r * 16 * V_DIM + v0;
      #pragma unroll
      for (int b = 0; b < 4; ++b) {
        long off = rb + b * 16;
        off = off > tlim ? tlim : off;
        tpA[r][b] = *(const f32x4*)(targets + off);
      }
    }

    f32x4 acc[4][4];
    #pragma unroll
    for (int a = 0; a < 4; ++a)
      #pragma unroll
      for (int b = 0; b < 4; ++b)
        acc[a][b] = (f32x4){0.f, 0.f, 0.f, 0.f};

    // ---- 2-phase pipelined K-loop: stage(next) -> compute(cur) -> bar ----
    #pragma unroll
    for (int ks = 0; ks < NSTEP; ++ks) {
      const int cb = (ks & 1) ? BUF1 : BUF0;
      const int nb = (ks & 1) ? BUF0 : BUF1;
      if (ks < NSTEP - 1)
        stage(nb, asrc, bsrc, (ks + 1) * BK);
      else if (!last)
        stage(nb, asrc, bsrc_next, 0);   // cross-tile prefetch of next k=0

      #pragma unroll
      for (int s = 0; s < 2; ++s) {
        short8 xf[4], wf[4];
        #pragma unroll
        for (int a = 0; a < 4; ++a)
          xf[a] = *(const short8*)(smem + cb + arow_b + a * 2048 +
                                   ((s * 64 + q * 16) ^ rm));
        #pragma unroll
        for (int b = 0; b < 4; ++b)
          wf[b] = *(const short8*)(smem + cb + 16384 + brow_b + b * 2048 +
                                   ((s * 64 + q * 16) ^ rm));
        #pragma unroll
        for (int a = 0; a < 4; ++a)
          #pragma unroll
          for (int b = 0; b < 4; ++b)
            acc[a][b] = __builtin_amdgcn_mfma_f32_16x16x32_bf16(
                wf[b], xf[a], acc[a][b], 0, 0, 0);
      }
      __syncthreads();
    }
    bsrc = bsrc_next;

    // ---- register prefetch, SECOND HALF: rows a={2,3} (post K-loop so the
    // regs aren't live across it; sched_barrier stops upward hoisting) ----
    __builtin_amdgcn_sched_barrier(0);
    #pragma unroll
    for (int r = 0; r < 2; ++r) {
      const long rb = trow0 + (long)(r + 2) * 16 * V_DIM + v0;
      #pragma unroll
      for (int b = 0; b < 4; ++b) {
        long off = rb + b * 16;
        off = off > tlim ? tlim : off;
        tpB[r][b] = *(const f32x4*)(targets + off);
      }
    }

    if (vt == VT_TOTAL - 1) {
      epi2<true>(tpA, bp, v0, 0, acc, ml, sl, mt, st, dd);
      epi2<true>(tpB, bp, v0, 2, acc, ml, sl, mt, st, dd);
    } else {
      epi2<false>(tpA, bp, v0, 0, acc, ml, sl, mt, st, dd);
      epi2<false>(tpB, bp, v0, 2, acc, ml, sl, mt, st, dd);
    }
  }

  // merge the 4 q-lanes (lane bits 4,5) holding disjoint vocab slices
  #pragma unroll
  for (int off = 16; off <= 32; off <<= 1) {
    #pragma unroll
    for (int a = 0; a < 4; ++a) {
      float ml2 = __shfl_xor(ml[a], off);
      float sl2 = __shfl_xor(sl[a], off);
      float mt2 = __shfl_xor(mt[a], off);
      float st2 = __shfl_xor(st[a], off);
      float dd2 = __shfl_xor(dd[a], off);
      float nm = fmaxf(ml[a], ml2);
      sl[a] = sl[a] * exp2f((ml[a] - nm) * LOG2E) + sl2 * exp2f((ml2 - nm) * LOG2E);
      ml[a] = nm;
      float nmt = fmaxf(mt[a], mt2);
      float e1 = exp2f((mt[a] - nmt) * LOG2E);
      float e2 = exp2f((mt2 - nmt) * LOG2E);
      st[a] = st[a] * e1 + st2 * e2;
      dd[a] = dd[a] * e1 + dd2 * e2;
      mt[a] = nmt;
    }
  }

  // cross-wn merge via LDS, one partial per (row, chunk)
  __syncthreads();
  float* M = (float*)smem;   // 128 rows x 5 floats = 2560 B
  if (wn == 1 && q == 0) {
    #pragma unroll
    for (int a = 0; a < 4; ++a) {
      int r = wm * 64 + a * 16 + c15;
      float* p = M + r * 5;
      p[0] = ml[a]; p[1] = sl[a]; p[2] = mt[a]; p[3] = st[a]; p[4] = dd[a];
    }
  }
  __syncthreads();
  if (wn == 0 && q == 0) {
    #pragma unroll
    for (int a = 0; a < 4; ++a) {
      int r = wm * 64 + a * 16 + c15;
      const float* p = M + r * 5;
      float ml2 = p[0], sl2 = p[1], mt2 = p[2], st2 = p[3], dd2 = p[4];
      float nm = fmaxf(ml[a], ml2);
      float slo = sl[a] * exp2f((ml[a] - nm) * LOG2E) + sl2 * exp2f((ml2 - nm) * LOG2E);
      float nmt = fmaxf(mt[a], mt2);
      float e1 = exp2f((mt[a] - nmt) * LOG2E);
      float e2 = exp2f((mt2 - nmt) * LOG2E);
      float sto = st[a] * e1 + st2 * e2;
      float ddo = dd[a] * e1 + dd2 * e2;
      long rg = (long)(brow * BM + r);
      float* o = partials + (rg * NCHUNK + chunk) * 5;
      o[0] = nm; o[1] = slo; o[2] = nmt; o[3] = sto; o[4] = ddo;
    }
  }
}

// ---------------- kernel C: merge partials -> per-row loss ----------------
__global__ void rowloss_kernel(const float* __restrict__ partials,
                               float* __restrict__ rowloss) {
  int r = blockIdx.x * blockDim.x + threadIdx.x;
  if (r >= N_ROWS) return;
  const float* p = partials + (long)r * NCHUNK * 5;
  float ml = -1e30f, sl = 0.f, mt = -1e30f, st = 0.f, dd = 0.f;
  for (int c = 0; c < NCHUNK; ++c) {
    float ml2 = p[0], sl2 = p[1], mt2 = p[2], st2 = p[3], dd2 = p[4];
    p += 5;
    float nm = fmaxf(ml, ml2);
    sl = sl * exp2f((ml - nm) * LOG2E) + sl2 * exp2f((ml2 - nm) * LOG2E);
    ml = nm;
    float nmt = fmaxf(mt, mt2);
    float e1 = exp2f((mt - nmt) * LOG2E);
    float e2 = exp2f((mt2 - nmt) * LOG2E);
    st = st * e1 + st2 * e2;
    dd = dd * e1 + dd2 * e2;
    mt = nmt;
  }
  float lse = ml + logf(sl);
  rowloss[r] = lse - dd / st;
}

// ---------------- kernel D: final scalar reduce ---------------------------
__global__ void final_kernel(const float* __restrict__ rowloss,
                             float* __restrict__ out) {
  __shared__ float sm[4];
  float s = 0.f;
  for (int i = threadIdx.x; i < N_ROWS; i += 256) s += rowloss[i];
  #pragma unroll
  for (int off = 32; off > 0; off >>= 1) s += __shfl_down(s, off);
  if ((threadIdx.x & 63) == 0) sm[threadIdx.x >> 6] = s;
  __syncthreads();
  if (threadIdx.x == 0) out[0] = (sm[0] + sm[1] + sm[2] + sm[3]) * (1.0f / (float)N_ROWS);
}

extern "C" void kernel_launch(void* const* d_in, const int* in_sizes, int n_in,
                              void* d_out, int out_size, void* d_ws, size_t ws_size,
                              hipStream_t stream) {
  const float* x       = (const float*)d_in[0];   // [4096, 512]
  const float* targets = (const float*)d_in[1];   // [4096, 50257]
  const float* weight  = (const float*)d_in[2];   // [50257, 512]
  const float* bias    = (const float*)d_in[3];   // [50257]
  float* out = (float*)d_out;

  char* ws = (char*)d_ws;
  __hip_bfloat16* Wb = (__hip_bfloat16*)ws;                     // 51,511,296 B
  size_t off = (size_t)V_PAD * H_DIM * 2;
  __hip_bfloat16* Xb = (__hip_bfloat16*)(ws + off);             //  4,194,304 B
  off += (size_t)N_ROWS * H_DIM * 2;
  float* partials = (float*)(ws + off);                         // 10,731,520 B
  off += (size_t)N_ROWS * NCHUNK * 5 * sizeof(float);
  float* rowloss = (float*)(ws + off);                          //     16,384 B

  convert_kernel<<<13600, 256, 0, stream>>>(x, weight, Xb, Wb);
  dim3 grid(N_ROWS / BM, NCHUNK);
  fused_kernel<<<grid, 256, 0, stream>>>(Xb, Wb, bias, targets, partials);
  rowloss_kernel<<<N_ROWS / 256, 256, 0, stream>>>(partials, rowloss);
  final_kernel<<<1, 256, 0, stream>>>(rowloss, out);
}

// Round 7
// 866.161 us; speedup vs baseline: 1.1451x; 1.1314x over previous
//
#include <hip/hip_runtime.h>
#include <hip/hip_bf16.h>

#define N_ROWS 4096
#define H_DIM  512
#define V_DIM  50257
#define BM 128
#define BN 128
#define BK 64
#define NSTEP (H_DIM / BK)      // 8
#define VT_TOTAL 393            // ceil(V/BN)
#define V_PAD (VT_TOTAL * BN)   // 50304
#define NCHUNK 131              // 393 = 3*131 -> every block exactly 3 tiles
#define LOG2E 1.4426950408889634f
#define BUF0 0
#define BUF1 32768

typedef __attribute__((ext_vector_type(8))) short short8;
typedef __attribute__((ext_vector_type(4))) float f32x4;

static __device__ __forceinline__ unsigned short f2bf(float f) {
  unsigned u = __float_as_uint(f);
  u = (u + 0x7fffu + ((u >> 16) & 1u)) >> 16;   // RNE
  return (unsigned short)u;
}

static __device__ __forceinline__ void gload_lds16(const void* g, void* l) {
  __builtin_amdgcn_global_load_lds(
      (const __attribute__((address_space(1))) void*)g,
      (__attribute__((address_space(3))) void*)l, 16, 0, 0);
}

// ---------------- kernel A: fp32 -> bf16 conversion (W padded to V_PAD) ----
__global__ void convert_kernel(const float* __restrict__ X,
                               const float* __restrict__ W,
                               __hip_bfloat16* __restrict__ Xb,
                               __hip_bfloat16* __restrict__ Wb) {
  const long wtot8 = (long)V_PAD * H_DIM / 8;   // 3,219,456
  const long xtot8 = (long)N_ROWS * H_DIM / 8;  //   262,144
  long i = (long)blockIdx.x * blockDim.x + threadIdx.x;
  unsigned short o[8];
  if (i < wtot8) {
    long base = i * 8;
    long row = base >> 9;   // /512
    if (row < V_DIM) {
      const float4* s = (const float4*)(W + base);
      float4 a = s[0], b = s[1];
      o[0]=f2bf(a.x); o[1]=f2bf(a.y); o[2]=f2bf(a.z); o[3]=f2bf(a.w);
      o[4]=f2bf(b.x); o[5]=f2bf(b.y); o[6]=f2bf(b.z); o[7]=f2bf(b.w);
    } else {
      #pragma unroll
      for (int k = 0; k < 8; ++k) o[k] = 0;
    }
    *(short8*)(Wb + base) = *(const short8*)o;
  } else if (i < wtot8 + xtot8) {
    long base = (i - wtot8) * 8;
    const float4* s = (const float4*)(X + base);
    float4 a = s[0], b = s[1];
    o[0]=f2bf(a.x); o[1]=f2bf(a.y); o[2]=f2bf(a.z); o[3]=f2bf(a.w);
    o[4]=f2bf(b.x); o[5]=f2bf(b.y); o[6]=f2bf(b.z); o[7]=f2bf(b.w);
    *(short8*)(Xb + base) = *(const short8*)o;
  }
}

// epilogue for ONE row-group A (template index: no runtime acc indexing)
template <bool GUARD, int A>
static __device__ __forceinline__ void epi1(
    const f32x4 (&tp)[4], const f32x4 (&bp)[4], int v0,
    const f32x4 (&acc)[4][4],
    float ml[4], float sl[4], float mt[4], float st[4], float dd[4]) {
  #pragma unroll
  for (int h = 0; h < 2; ++h) {          // halves: b = {2h, 2h+1}
    float T[8], L[8];
    #pragma unroll
    for (int bb = 0; bb < 2; ++bb) {
      const int b = 2 * h + bb;
      #pragma unroll
      for (int j = 0; j < 4; ++j) {
        const int k = bb * 4 + j;
        const bool ok = !GUARD || (v0 + b * 16 + j < V_DIM);
        L[k] = ok ? (acc[A][b][j] + bp[b][j]) : -1e30f;
        T[k] = ok ? tp[b][j] : -1e30f;
      }
    }
    // logits lse (online, defer-max thr=12)
    float g = fmaxf(fmaxf(fmaxf(L[0], L[1]), fmaxf(L[2], L[3])),
                    fmaxf(fmaxf(L[4], L[5]), fmaxf(L[6], L[7])));
    if (g > ml[A] + 12.f) {
      sl[A] *= exp2f((ml[A] - g) * LOG2E);
      ml[A] = g;
    }
    float bl = ml[A] * LOG2E;
    float ss = 0.f;
    #pragma unroll
    for (int k = 0; k < 8; ++k)
      ss += exp2f(__builtin_fmaf(L[k], LOG2E, -bl));
    sl[A] += ss;
    // targets softmax num/denom (online, defer-max thr=12)
    float gt = fmaxf(fmaxf(fmaxf(T[0], T[1]), fmaxf(T[2], T[3])),
                     fmaxf(fmaxf(T[4], T[5]), fmaxf(T[6], T[7])));
    if (gt > mt[A] + 12.f) {
      float sc = exp2f((mt[A] - gt) * LOG2E);
      st[A] *= sc; dd[A] *= sc; mt[A] = gt;
    }
    float bt = mt[A] * LOG2E;
    float s2 = 0.f, d2 = 0.f;
    #pragma unroll
    for (int k = 0; k < 8; ++k) {
      float e = exp2f(__builtin_fmaf(T[k], LOG2E, -bt));
      s2 += e;
      d2 = __builtin_fmaf(e, L[k], d2);
    }
    st[A] += s2; dd[A] += d2;
  }
}

// ---------------- kernel B: fused GEMM + online softmax stats -------------
// Grid (32, NCHUNK). Block 256 = 4 waves (2x2 over the 128x128 tile).
// BK=64 double-buffered 2-phase K-loop; LDS XOR-swizzle. Targets loads
// issued ONLY after the K-loop, max 3 rows (48 VGPR) live at once -> no
// spill (round-5/6's 1.04 GB WRITE_SIZE == tp+bp spilled once per tile).
__global__ __launch_bounds__(256, 2)
void fused_kernel(const __hip_bfloat16* __restrict__ Xb,
                  const __hip_bfloat16* __restrict__ Wb,
                  const float* __restrict__ bias,
                  const float* __restrict__ targets,
                  float* __restrict__ partials) {
  __shared__ __align__(16) char smem[65536];   // 2 x {A 16K, B 16K}

  const int tid  = threadIdx.x;
  const int lane = tid & 63;
  const int wid  = tid >> 6;
  const int wm   = wid >> 1;
  const int wn   = wid & 1;
  const int q    = lane >> 4;
  const int c15  = lane & 15;
  const int brow = blockIdx.x;
  const int chunk = blockIdx.y;

  float ml[4], sl[4], mt[4], st[4], dd[4];
  #pragma unroll
  for (int a = 0; a < 4; ++a) {
    ml[a] = -1e30f; sl[a] = 0.f; mt[a] = -1e30f; st[a] = 0.f; dd[a] = 0.f;
  }

  // staging precompute: thread t writes LDS bytes linearly; source element
  // offset pre-swizzled so a swizzled ds_read reads it back.
  const int srow8 = tid >> 3;                               // 0..31
  const int soff  = ((tid & 7) * 8) ^ ((srow8 & 7) * 8);    // elems in [0,64)
  const __hip_bfloat16* asrc = Xb + (long)(brow * BM + srow8) * H_DIM + soff;

  // read precompute
  const int rm      = (c15 & 7) << 4;          // byte XOR mask
  const int arow_b  = (wm * 64 + c15) * 128;   // + a*2048
  const int brow_b  = (wn * 64 + c15) * 128;   // + b*2048 (+16384 A-region)

  auto stage = [&](int bufb, const __hip_bfloat16* a_s,
                   const __hip_bfloat16* b_s, int kk) {
    #pragma unroll
    for (int i = 0; i < 4; ++i)
      gload_lds16(a_s + (long)i * 32 * H_DIM + kk,
                  smem + bufb + i * 4096 + tid * 16);
    #pragma unroll
    for (int i = 0; i < 4; ++i)
      gload_lds16(b_s + (long)i * 32 * H_DIM + kk,
                  smem + bufb + 16384 + i * 4096 + tid * 16);
  };

  // per-thread target row base
  const long trow0 = (long)(brow * BM + wm * 64 + c15) * V_DIM;
  const long tlim  = (long)N_ROWS * V_DIM - 4;

  // prologue: stage first tile's k=0 into buf0
  const __hip_bfloat16* bsrc = Wb + (long)(chunk * BN + srow8) * H_DIM + soff;
  stage(BUF0, asrc, bsrc, 0);
  __syncthreads();

  #pragma unroll 1
  for (int vt = chunk; vt < VT_TOTAL; vt += NCHUNK) {
    const int vbase = vt * BN;
    const int v0 = vbase + wn * 64 + q * 4;
    const bool last = (vt + NCHUNK >= VT_TOTAL);
    const __hip_bfloat16* bsrc_next =
        Wb + (long)((vt + NCHUNK) * BN + srow8) * H_DIM + soff;

    f32x4 acc[4][4];
    #pragma unroll
    for (int a = 0; a < 4; ++a)
      #pragma unroll
      for (int b = 0; b < 4; ++b)
        acc[a][b] = (f32x4){0.f, 0.f, 0.f, 0.f};

    // ---- 2-phase pipelined K-loop: stage(next) -> compute(cur) -> bar ----
    #pragma unroll
    for (int ks = 0; ks < NSTEP; ++ks) {
      const int cb = (ks & 1) ? BUF1 : BUF0;
      const int nb = (ks & 1) ? BUF0 : BUF1;
      if (ks < NSTEP - 1)
        stage(nb, asrc, bsrc, (ks + 1) * BK);
      else if (!last)
        stage(nb, asrc, bsrc_next, 0);   // cross-tile prefetch of next k=0

      #pragma unroll
      for (int s = 0; s < 2; ++s) {
        short8 xf[4], wf[4];
        #pragma unroll
        for (int a = 0; a < 4; ++a)
          xf[a] = *(const short8*)(smem + cb + arow_b + a * 2048 +
                                   ((s * 64 + q * 16) ^ rm));
        #pragma unroll
        for (int b = 0; b < 4; ++b)
          wf[b] = *(const short8*)(smem + cb + 16384 + brow_b + b * 2048 +
                                   ((s * 64 + q * 16) ^ rm));
        #pragma unroll
        for (int a = 0; a < 4; ++a)
          #pragma unroll
          for (int b = 0; b < 4; ++b)
            acc[a][b] = __builtin_amdgcn_mfma_f32_16x16x32_bf16(
                wf[b], xf[a], acc[a][b], 0, 0, 0);
      }
      __syncthreads();
    }
    bsrc = bsrc_next;

    // ---- epilogue: targets/bias loads issued ONLY here, <=3 rows live ----
    f32x4 bp[4], t0[4], t1[4], t2[4], t3[4];
    auto loadrow = [&](f32x4 (&dst)[4], int a) {
      const long rb = trow0 + (long)a * 16 * V_DIM + v0;
      #pragma unroll
      for (int b = 0; b < 4; ++b) {
        long off = rb + (long)(b * 16);
        off = off > tlim ? tlim : off;
        dst[b] = *(const f32x4*)(targets + off);
      }
    };

    __builtin_amdgcn_sched_barrier(0);
    #pragma unroll
    for (int b = 0; b < 4; ++b) {
      int bo = v0 + b * 16;
      bo = bo > (V_DIM - 4) ? (V_DIM - 4) : bo;
      bp[b] = *(const f32x4*)(bias + bo);
    }
    loadrow(t0, 0);
    loadrow(t1, 1);
    __builtin_amdgcn_sched_barrier(0);   // all 12 loads issued before math

    if (vt == VT_TOTAL - 1) {
      epi1<true, 0>(t0, bp, v0, acc, ml, sl, mt, st, dd);
      loadrow(t2, 2);
      epi1<true, 1>(t1, bp, v0, acc, ml, sl, mt, st, dd);
      loadrow(t3, 3);
      epi1<true, 2>(t2, bp, v0, acc, ml, sl, mt, st, dd);
      epi1<true, 3>(t3, bp, v0, acc, ml, sl, mt, st, dd);
    } else {
      epi1<false, 0>(t0, bp, v0, acc, ml, sl, mt, st, dd);
      loadrow(t2, 2);
      epi1<false, 1>(t1, bp, v0, acc, ml, sl, mt, st, dd);
      loadrow(t3, 3);
      epi1<false, 2>(t2, bp, v0, acc, ml, sl, mt, st, dd);
      epi1<false, 3>(t3, bp, v0, acc, ml, sl, mt, st, dd);
    }
  }

  // merge the 4 q-lanes (lane bits 4,5) holding disjoint vocab slices
  #pragma unroll
  for (int off = 16; off <= 32; off <<= 1) {
    #pragma unroll
    for (int a = 0; a < 4; ++a) {
      float ml2 = __shfl_xor(ml[a], off);
      float sl2 = __shfl_xor(sl[a], off);
      float mt2 = __shfl_xor(mt[a], off);
      float st2 = __shfl_xor(st[a], off);
      float dd2 = __shfl_xor(dd[a], off);
      float nm = fmaxf(ml[a], ml2);
      sl[a] = sl[a] * exp2f((ml[a] - nm) * LOG2E) + sl2 * exp2f((ml2 - nm) * LOG2E);
      ml[a] = nm;
      float nmt = fmaxf(mt[a], mt2);
      float e1 = exp2f((mt[a] - nmt) * LOG2E);
      float e2 = exp2f((mt2 - nmt) * LOG2E);
      st[a] = st[a] * e1 + st2 * e2;
      dd[a] = dd[a] * e1 + dd2 * e2;
      mt[a] = nmt;
    }
  }

  // cross-wn merge via LDS, one partial per (row, chunk)
  __syncthreads();
  float* M = (float*)smem;   // 128 rows x 5 floats = 2560 B
  if (wn == 1 && q == 0) {
    #pragma unroll
    for (int a = 0; a < 4; ++a) {
      int r = wm * 64 + a * 16 + c15;
      float* p = M + r * 5;
      p[0] = ml[a]; p[1] = sl[a]; p[2] = mt[a]; p[3] = st[a]; p[4] = dd[a];
    }
  }
  __syncthreads();
  if (wn == 0 && q == 0) {
    #pragma unroll
    for (int a = 0; a < 4; ++a) {
      int r = wm * 64 + a * 16 + c15;
      const float* p = M + r * 5;
      float ml2 = p[0], sl2 = p[1], mt2 = p[2], st2 = p[3], dd2 = p[4];
      float nm = fmaxf(ml[a], ml2);
      float slo = sl[a] * exp2f((ml[a] - nm) * LOG2E) + sl2 * exp2f((ml2 - nm) * LOG2E);
      float nmt = fmaxf(mt[a], mt2);
      float e1 = exp2f((mt[a] - nmt) * LOG2E);
      float e2 = exp2f((mt2 - nmt) * LOG2E);
      float sto = st[a] * e1 + st2 * e2;
      float ddo = dd[a] * e1 + dd2 * e2;
      long rg = (long)(brow * BM + r);
      float* o = partials + (rg * NCHUNK + chunk) * 5;
      o[0] = nm; o[1] = slo; o[2] = nmt; o[3] = sto; o[4] = ddo;
    }
  }
}

// ---------------- kernel C: merge partials -> per-row loss ----------------
__global__ void rowloss_kernel(const float* __restrict__ partials,
                               float* __restrict__ rowloss) {
  int r = blockIdx.x * blockDim.x + threadIdx.x;
  if (r >= N_ROWS) return;
  const float* p = partials + (long)r * NCHUNK * 5;
  float ml = -1e30f, sl = 0.f, mt = -1e30f, st = 0.f, dd = 0.f;
  for (int c = 0; c < NCHUNK; ++c) {
    float ml2 = p[0], sl2 = p[1], mt2 = p[2], st2 = p[3], dd2 = p[4];
    p += 5;
    float nm = fmaxf(ml, ml2);
    sl = sl * exp2f((ml - nm) * LOG2E) + sl2 * exp2f((ml2 - nm) * LOG2E);
    ml = nm;
    float nmt = fmaxf(mt, mt2);
    float e1 = exp2f((mt - nmt) * LOG2E);
    float e2 = exp2f((mt2 - nmt) * LOG2E);
    st = st * e1 + st2 * e2;
    dd = dd * e1 + dd2 * e2;
    mt = nmt;
  }
  float lse = ml + logf(sl);
  rowloss[r] = lse - dd / st;
}

// ---------------- kernel D: final scalar reduce ---------------------------
__global__ void final_kernel(const float* __restrict__ rowloss,
                             float* __restrict__ out) {
  __shared__ float sm[4];
  float s = 0.f;
  for (int i = threadIdx.x; i < N_ROWS; i += 256) s += rowloss[i];
  #pragma unroll
  for (int off = 32; off > 0; off >>= 1) s += __shfl_down(s, off);
  if ((threadIdx.x & 63) == 0) sm[threadIdx.x >> 6] = s;
  __syncthreads();
  if (threadIdx.x == 0) out[0] = (sm[0] + sm[1] + sm[2] + sm[3]) * (1.0f / (float)N_ROWS);
}

extern "C" void kernel_launch(void* const* d_in, const int* in_sizes, int n_in,
                              void* d_out, int out_size, void* d_ws, size_t ws_size,
                              hipStream_t stream) {
  const float* x       = (const float*)d_in[0];   // [4096, 512]
  const float* targets = (const float*)d_in[1];   // [4096, 50257]
  const float* weight  = (const float*)d_in[2];   // [50257, 512]
  const float* bias    = (const float*)d_in[3];   // [50257]
  float* out = (float*)d_out;

  char* ws = (char*)d_ws;
  __hip_bfloat16* Wb = (__hip_bfloat16*)ws;                     // 51,511,296 B
  size_t off = (size_t)V_PAD * H_DIM * 2;
  __hip_bfloat16* Xb = (__hip_bfloat16*)(ws + off);             //  4,194,304 B
  off += (size_t)N_ROWS * H_DIM * 2;
  float* partials = (float*)(ws + off);                         // 10,731,520 B
  off += (size_t)N_ROWS * NCHUNK * 5 * sizeof(float);
  float* rowloss = (float*)(ws + off);                          //     16,384 B

  convert_kernel<<<13600, 256, 0, stream>>>(x, weight, Xb, Wb);
  dim3 grid(N_ROWS / BM, NCHUNK);
  fused_kernel<<<grid, 256, 0, stream>>>(Xb, Wb, bias, targets, partials);
  rowloss_kernel<<<N_ROWS / 256, 256, 0, stream>>>(partials, rowloss);
  final_kernel<<<1, 256, 0, stream>>>(rowloss, out);
}

// Round 8
// 520.460 us; speedup vs baseline: 1.9058x; 1.6642x over previous
//
#include <hip/hip_runtime.h>
#include <hip/hip_bf16.h>

#define N_ROWS 4096
#define H_DIM  512
#define V_DIM  50257
#define BM 128
#define BN 128
#define BK 64
#define NSTEP (H_DIM / BK)      // 8
#define VT_TOTAL 393            // ceil(V/BN)
#define V_PAD (VT_TOTAL * BN)   // 50304
#define NCHUNK 131              // 393 = 3*131 -> every block exactly 3 tiles
#define LOG2E 1.4426950408889634f
#define BUF0 0
#define BUF1 32768

typedef __attribute__((ext_vector_type(8))) short short8;
typedef __attribute__((ext_vector_type(4))) float f32x4;

static __device__ __forceinline__ unsigned short f2bf(float f) {
  unsigned u = __float_as_uint(f);
  u = (u + 0x7fffu + ((u >> 16) & 1u)) >> 16;   // RNE
  return (unsigned short)u;
}

static __device__ __forceinline__ void gload_lds16(const void* g, void* l) {
  __builtin_amdgcn_global_load_lds(
      (const __attribute__((address_space(1))) void*)g,
      (__attribute__((address_space(3))) void*)l, 16, 0, 0);
}

// ---------------- kernel A: fp32 -> bf16 conversion (W padded to V_PAD) ----
__global__ void convert_kernel(const float* __restrict__ X,
                               const float* __restrict__ W,
                               __hip_bfloat16* __restrict__ Xb,
                               __hip_bfloat16* __restrict__ Wb) {
  const long wtot8 = (long)V_PAD * H_DIM / 8;   // 3,219,456
  const long xtot8 = (long)N_ROWS * H_DIM / 8;  //   262,144
  long i = (long)blockIdx.x * blockDim.x + threadIdx.x;
  unsigned short o[8];
  if (i < wtot8) {
    long base = i * 8;
    long row = base >> 9;   // /512
    if (row < V_DIM) {
      const float4* s = (const float4*)(W + base);
      float4 a = s[0], b = s[1];
      o[0]=f2bf(a.x); o[1]=f2bf(a.y); o[2]=f2bf(a.z); o[3]=f2bf(a.w);
      o[4]=f2bf(b.x); o[5]=f2bf(b.y); o[6]=f2bf(b.z); o[7]=f2bf(b.w);
    } else {
      #pragma unroll
      for (int k = 0; k < 8; ++k) o[k] = 0;
    }
    *(short8*)(Wb + base) = *(const short8*)o;
  } else if (i < wtot8 + xtot8) {
    long base = (i - wtot8) * 8;
    const float4* s = (const float4*)(X + base);
    float4 a = s[0], b = s[1];
    o[0]=f2bf(a.x); o[1]=f2bf(a.y); o[2]=f2bf(a.z); o[3]=f2bf(a.w);
    o[4]=f2bf(b.x); o[5]=f2bf(b.y); o[6]=f2bf(b.z); o[7]=f2bf(b.w);
    *(short8*)(Xb + base) = *(const short8*)o;
  }
}

// stats update for one 16-col chunk (values L include bias)
template <bool GUARD>
static __device__ __forceinline__ void chunk_stats(
    const f32x4 (&T)[4], const f32x4 (&L)[4], int gcol0,
    float& mlr, float& slr, float& mtr, float& str, float& ddr) {
  float Lv[16], Tv[16];
  #pragma unroll
  for (int c = 0; c < 4; ++c)
    #pragma unroll
    for (int j = 0; j < 4; ++j) {
      const int k = c * 4 + j;
      const bool ok = !GUARD || (gcol0 + c * 4 + j < V_DIM);
      Lv[k] = ok ? L[c][j] : -1e30f;
      Tv[k] = ok ? T[c][j] : -1e30f;
    }
  float g = Lv[0];
  #pragma unroll
  for (int k = 1; k < 16; ++k) g = fmaxf(g, Lv[k]);
  if (g > mlr + 12.f) { slr *= exp2f((mlr - g) * LOG2E); mlr = g; }
  float bl = mlr * LOG2E;
  float ss = 0.f;
  #pragma unroll
  for (int k = 0; k < 16; ++k) ss += exp2f(__builtin_fmaf(Lv[k], LOG2E, -bl));
  slr += ss;
  float gt = Tv[0];
  #pragma unroll
  for (int k = 1; k < 16; ++k) gt = fmaxf(gt, Tv[k]);
  if (gt > mtr + 12.f) {
    float sc = exp2f((mtr - gt) * LOG2E);
    str *= sc; ddr *= sc; mtr = gt;
  }
  float bt = mtr * LOG2E;
  float s2 = 0.f, d2 = 0.f;
  #pragma unroll
  for (int k = 0; k < 16; ++k) {
    float e = exp2f(__builtin_fmaf(Tv[k], LOG2E, -bt));
    s2 += e;
    d2 = __builtin_fmaf(e, Lv[k], d2);
  }
  str += s2; ddr += d2;
}

// streaming stats for one tile: 64 cols (4 chunks), 2-deep T pipeline
template <bool GUARD>
static __device__ __forceinline__ void stream_tile(
    const float* __restrict__ targets, const char* __restrict__ Lrow,
    long growVD, int vbase, int cb0, int rsw, long tlim,
    float& mlr, float& slr, float& mtr, float& str, float& ddr) {
  f32x4 T0[4], T1[4], L[4];
  auto LOADT = [&](f32x4 (&D)[4], int i) {
    #pragma unroll
    for (int c = 0; c < 4; ++c) {
      long off = growVD + vbase + cb0 + i * 16 + c * 4;
      if (GUARD) off = off > tlim ? tlim : off;
      D[c] = *(const f32x4*)(targets + off);
    }
  };
  auto LOADL = [&](int i) {
    #pragma unroll
    for (int c = 0; c < 4; ++c)
      L[c] = *(const f32x4*)(Lrow + (((cb0 + i * 16 + c * 4) * 4) ^ rsw));
  };
  LOADT(T0, 0); LOADT(T1, 1);
  LOADL(0); chunk_stats<GUARD>(T0, L, vbase + cb0 +  0, mlr, slr, mtr, str, ddr);
  LOADT(T0, 2);
  LOADL(1); chunk_stats<GUARD>(T1, L, vbase + cb0 + 16, mlr, slr, mtr, str, ddr);
  LOADT(T1, 3);
  LOADL(2); chunk_stats<GUARD>(T0, L, vbase + cb0 + 32, mlr, slr, mtr, str, ddr);
  LOADL(3); chunk_stats<GUARD>(T1, L, vbase + cb0 + 48, mlr, slr, mtr, str, ddr);
}

// ---------------- kernel B: fused GEMM + online softmax stats -------------
// Grid (32, NCHUNK). Block 256 = 4 waves. Per tile: (1) BK=64 dbuf K-loop,
// (2) dump acc+bias -> LDS L[128][128] f32 (XOR-swizzled), acc dies,
// (3) streaming stats: thread owns (row=tid>>1, half=tid&1), 5 regs state.
// No phase keeps targets tile + acc co-resident -> no scratch spill.
__global__ __launch_bounds__(256, 2)
void fused_kernel(const __hip_bfloat16* __restrict__ Xb,
                  const __hip_bfloat16* __restrict__ Wb,
                  const float* __restrict__ bias,
                  const float* __restrict__ targets,
                  float* __restrict__ partials) {
  __shared__ __align__(16) char smem[65536];   // staging dbuf == L tile

  const int tid  = threadIdx.x;
  const int lane = tid & 63;
  const int wid  = tid >> 6;
  const int wm   = wid >> 1;
  const int wn   = wid & 1;
  const int q    = lane >> 4;
  const int c15  = lane & 15;
  const int brow = blockIdx.x;
  const int chunk = blockIdx.y;

  // persistent streaming stats: row = tid>>1, half = tid&1
  float mlr = -1e30f, slr = 0.f, mtr = -1e30f, str = 0.f, ddr = 0.f;

  // staging precompute (linear LDS writes, pre-swizzled global source)
  const int srow8 = tid >> 3;                               // 0..31
  const int soff  = ((tid & 7) * 8) ^ ((srow8 & 7) * 8);    // elems in [0,64)
  const __hip_bfloat16* asrc = Xb + (long)(brow * BM + srow8) * H_DIM + soff;

  // fragment-read precompute
  const int rm      = (c15 & 7) << 4;          // byte XOR mask
  const int arow_b  = (wm * 64 + c15) * 128;   // + a*2048
  const int brow_b  = (wn * 64 + c15) * 128;   // + b*2048 (+16384 B-region)

  auto stage = [&](int bufb, const __hip_bfloat16* a_s,
                   const __hip_bfloat16* b_s, int kk) {
    #pragma unroll
    for (int i = 0; i < 4; ++i)
      gload_lds16(a_s + (long)i * 32 * H_DIM + kk,
                  smem + bufb + i * 4096 + tid * 16);
    #pragma unroll
    for (int i = 0; i < 4; ++i)
      gload_lds16(b_s + (long)i * 32 * H_DIM + kk,
                  smem + bufb + 16384 + i * 4096 + tid * 16);
  };

  // streaming-phase precompute
  const int srow  = tid >> 1;                  // 0..127
  const int shalf = tid & 1;
  const int cb0   = shalf * 64;
  const long grow   = (long)(brow * BM + srow);
  const long growVD = grow * V_DIM;
  const long tlim   = (long)N_ROWS * V_DIM - 4;
  const char* Lrow  = smem + srow * 512;
  const int rsw     = (srow & 7) << 4;

  #pragma unroll 1
  for (int vt = chunk; vt < VT_TOTAL; vt += NCHUNK) {
    const int vbase = vt * BN;
    const int v0 = vbase + wn * 64 + q * 4;

    // ---- stage k=0 (previous tile's stream phase synced before this) ----
    const __hip_bfloat16* bsrc = Wb + (long)(vbase + srow8) * H_DIM + soff;
    stage(BUF0, asrc, bsrc, 0);
    __syncthreads();

    f32x4 acc[4][4];
    #pragma unroll
    for (int a = 0; a < 4; ++a)
      #pragma unroll
      for (int b = 0; b < 4; ++b)
        acc[a][b] = (f32x4){0.f, 0.f, 0.f, 0.f};

    // ---- 2-phase pipelined K-loop ----
    #pragma unroll
    for (int ks = 0; ks < NSTEP; ++ks) {
      const int cb = (ks & 1) ? BUF1 : BUF0;
      const int nb = (ks & 1) ? BUF0 : BUF1;
      if (ks < NSTEP - 1)
        stage(nb, asrc, bsrc, (ks + 1) * BK);

      #pragma unroll
      for (int s = 0; s < 2; ++s) {
        short8 xf[4], wf[4];
        #pragma unroll
        for (int a = 0; a < 4; ++a)
          xf[a] = *(const short8*)(smem + cb + arow_b + a * 2048 +
                                   ((s * 64 + q * 16) ^ rm));
        #pragma unroll
        for (int b = 0; b < 4; ++b)
          wf[b] = *(const short8*)(smem + cb + 16384 + brow_b + b * 2048 +
                                   ((s * 64 + q * 16) ^ rm));
        #pragma unroll
        for (int a = 0; a < 4; ++a)
          #pragma unroll
          for (int b = 0; b < 4; ++b)
            acc[a][b] = __builtin_amdgcn_mfma_f32_16x16x32_bf16(
                wf[b], xf[a], acc[a][b], 0, 0, 0);
      }
      __syncthreads();
    }

    // ---- dump acc + bias -> LDS L[128][128] f32 (swizzled); acc dies ----
    f32x4 bp[4];
    #pragma unroll
    for (int b = 0; b < 4; ++b) {
      int bo = v0 + b * 16;
      bo = bo > (V_DIM - 4) ? (V_DIM - 4) : bo;
      bp[b] = *(const f32x4*)(bias + bo);
    }
    #pragma unroll
    for (int a = 0; a < 4; ++a) {
      const int row = wm * 64 + a * 16 + c15;
      char* rbase = smem + row * 512;
      #pragma unroll
      for (int b = 0; b < 4; ++b) {
        f32x4 v;
        #pragma unroll
        for (int j = 0; j < 4; ++j) v[j] = acc[a][b][j] + bp[b][j];
        *(f32x4*)(rbase + ((wn * 256 + b * 64 + q * 16) ^ rm)) = v;
      }
    }
    __syncthreads();

    // ---- streaming stats phase ----
    if (vt == VT_TOTAL - 1)
      stream_tile<true >(targets, Lrow, growVD, vbase, cb0, rsw, tlim,
                         mlr, slr, mtr, str, ddr);
    else
      stream_tile<false>(targets, Lrow, growVD, vbase, cb0, rsw, tlim,
                         mlr, slr, mtr, str, ddr);
    __syncthreads();   // L fully read before next tile's stage overwrites
  }

  // merge the two halves of each row (lanes 2k / 2k+1)
  {
    float ml2 = __shfl_xor(mlr, 1);
    float sl2 = __shfl_xor(slr, 1);
    float mt2 = __shfl_xor(mtr, 1);
    float st2 = __shfl_xor(str, 1);
    float dd2 = __shfl_xor(ddr, 1);
    float nm = fmaxf(mlr, ml2);
    float slo = slr * exp2f((mlr - nm) * LOG2E) + sl2 * exp2f((ml2 - nm) * LOG2E);
    float nmt = fmaxf(mtr, mt2);
    float e1 = exp2f((mtr - nmt) * LOG2E);
    float e2 = exp2f((mt2 - nmt) * LOG2E);
    float sto = str * e1 + st2 * e2;
    float ddo = ddr * e1 + dd2 * e2;
    if (shalf == 0) {
      float* o = partials + (grow * NCHUNK + chunk) * 5;
      o[0] = nm; o[1] = slo; o[2] = nmt; o[3] = sto; o[4] = ddo;
    }
  }
}

// ---------------- kernel C: merge partials -> per-row loss ----------------
__global__ void rowloss_kernel(const float* __restrict__ partials,
                               float* __restrict__ rowloss) {
  int r = blockIdx.x * blockDim.x + threadIdx.x;
  if (r >= N_ROWS) return;
  const float* p = partials + (long)r * NCHUNK * 5;
  float ml = -1e30f, sl = 0.f, mt = -1e30f, st = 0.f, dd = 0.f;
  for (int c = 0; c < NCHUNK; ++c) {
    float ml2 = p[0], sl2 = p[1], mt2 = p[2], st2 = p[3], dd2 = p[4];
    p += 5;
    float nm = fmaxf(ml, ml2);
    sl = sl * exp2f((ml - nm) * LOG2E) + sl2 * exp2f((ml2 - nm) * LOG2E);
    ml = nm;
    float nmt = fmaxf(mt, mt2);
    float e1 = exp2f((mt - nmt) * LOG2E);
    float e2 = exp2f((mt2 - nmt) * LOG2E);
    st = st * e1 + st2 * e2;
    dd = dd * e1 + dd2 * e2;
    mt = nmt;
  }
  float lse = ml + logf(sl);
  rowloss[r] = lse - dd / st;
}

// ---------------- kernel D: final scalar reduce ---------------------------
__global__ void final_kernel(const float* __restrict__ rowloss,
                             float* __restrict__ out) {
  __shared__ float sm[4];
  float s = 0.f;
  for (int i = threadIdx.x; i < N_ROWS; i += 256) s += rowloss[i];
  #pragma unroll
  for (int off = 32; off > 0; off >>= 1) s += __shfl_down(s, off);
  if ((threadIdx.x & 63) == 0) sm[threadIdx.x >> 6] = s;
  __syncthreads();
  if (threadIdx.x == 0) out[0] = (sm[0] + sm[1] + sm[2] + sm[3]) * (1.0f / (float)N_ROWS);
}

extern "C" void kernel_launch(void* const* d_in, const int* in_sizes, int n_in,
                              void* d_out, int out_size, void* d_ws, size_t ws_size,
                              hipStream_t stream) {
  const float* x       = (const float*)d_in[0];   // [4096, 512]
  const float* targets = (const float*)d_in[1];   // [4096, 50257]
  const float* weight  = (const float*)d_in[2];   // [50257, 512]
  const float* bias    = (const float*)d_in[3];   // [50257]
  float* out = (float*)d_out;

  char* ws = (char*)d_ws;
  __hip_bfloat16* Wb = (__hip_bfloat16*)ws;                     // 51,511,296 B
  size_t off = (size_t)V_PAD * H_DIM * 2;
  __hip_bfloat16* Xb = (__hip_bfloat16*)(ws + off);             //  4,194,304 B
  off += (size_t)N_ROWS * H_DIM * 2;
  float* partials = (float*)(ws + off);                         // 10,731,520 B
  off += (size_t)N_ROWS * NCHUNK * 5 * sizeof(float);
  float* rowloss = (float*)(ws + off);                          //     16,384 B

  convert_kernel<<<13600, 256, 0, stream>>>(x, weight, Xb, Wb);
  dim3 grid(N_ROWS / BM, NCHUNK);
  fused_kernel<<<grid, 256, 0, stream>>>(Xb, Wb, bias, targets, partials);
  rowloss_kernel<<<N_ROWS / 256, 256, 0, stream>>>(partials, rowloss);
  final_kernel<<<1, 256, 0, stream>>>(rowloss, out);
}